// Round 8
// baseline (117.008 us; speedup 1.0000x reference)
//
#include <hip/hip_runtime.h>
#include <math.h>

#define NQ   10
#define DIMQ 1024
#define BATCH_ROWS 16384

typedef unsigned uv2 __attribute__((ext_vector_type(2)));
typedef float f32x2 __attribute__((ext_vector_type(2)));
typedef float f32x4 __attribute__((ext_vector_type(4)));

#if __has_builtin(__builtin_amdgcn_permlane32_swap)
#define HAS_PLS32 1
#else
#define HAS_PLS32 0
#endif
#if __has_builtin(__builtin_amdgcn_permlane16_swap)
#define HAS_PLS16 1
#else
#define HAS_PLS16 0
#endif

// ---------------------------------------------------------------------------
// Precompute: one fused 2x2 complex matrix per qubit (validated R6/R7).
//   M_k = D(phi)*BS*D(theta)*BS*D(alpha,beta)
//   = 0.5*[[p*u*(t-1), p*v*i(t+1)], [u*i(t+1), v*(1-t)]]
// ---------------------------------------------------------------------------
__device__ __forceinline__ float2 cmulc(float2 a, float2 b) {
    return make_float2(a.x * b.x - a.y * b.y, a.x * b.y + a.y * b.x);
}

__global__ void qmat_precompute(const float* __restrict__ alphas,
                                const float* __restrict__ betas,
                                const float* __restrict__ thetas,
                                const float* __restrict__ phis,
                                float* __restrict__ M) {
    const int b = threadIdx.x;
    if (b >= NQ) return;
    const int q = NQ - 1 - b;
    float sa, ca, sb, cb, st, ct, sp, cp;
    sincosf(alphas[q], &sa, &ca);
    sincosf(betas[q],  &sb, &cb);
    sincosf(thetas[q], &st, &ct);
    sincosf(phis[q],   &sp, &cp);
    const float2 u = make_float2(ca, sa), v = make_float2(cb, sb), p = make_float2(cp, sp);
    const float2 tm1  = make_float2(ct - 1.f, st);
    const float2 itp1 = make_float2(-st, ct + 1.f);
    const float2 omt  = make_float2(1.f - ct, -st);
    float2 m00 = cmulc(cmulc(p, u), tm1);
    float2 m01 = cmulc(cmulc(p, v), itp1);
    float2 m10 = cmulc(u, itp1);
    float2 m11 = cmulc(v, omt);
    const float s = 0.5f;
    M[b * 8 + 0] = m00.x * s; M[b * 8 + 1] = m00.y * s;
    M[b * 8 + 2] = m01.x * s; M[b * 8 + 3] = m01.y * s;
    M[b * 8 + 4] = m10.x * s; M[b * 8 + 5] = m10.y * s;
    M[b * 8 + 6] = m11.x * s; M[b * 8 + 7] = m11.y * s;
}

// ---------------------------------------------------------------------------
// Cross-lane primitives (scalar + packed wrappers)
// ---------------------------------------------------------------------------
template <int CTRL>
__device__ __forceinline__ float dpp_mov(float x) {
    return __int_as_float(
        __builtin_amdgcn_update_dpp(0, __float_as_int(x), CTRL, 0xF, 0xF, true));
}
template <int PAT>
__device__ __forceinline__ float ds_swz(float x) {
    return __int_as_float(__builtin_amdgcn_ds_swizzle(__float_as_int(x), PAT));
}
template <int CTRL>
__device__ __forceinline__ f32x2 pk_dpp(f32x2 v) {
    return (f32x2){dpp_mov<CTRL>(v.x), dpp_mov<CTRL>(v.y)};
}
template <int PAT>
__device__ __forceinline__ f32x2 pk_swz(f32x2 v) {
    return (f32x2){ds_swz<PAT>(v.x), ds_swz<PAT>(v.y)};
}
__device__ __forceinline__ f32x2 pk_shfl_xor(f32x2 v, int m) {
    return (f32x2){__shfl_xor(v.x, m, 64), __shfl_xor(v.y, m, 64)};
}
__device__ __forceinline__ f32x2 pk_swap(f32x2 v) { return (f32x2){v.y, v.x}; }

#define DPP_XOR1 0xB1
#define DPP_XOR2 0x4E
#define SWZ_XOR4 0x101F
#define SWZ_XOR8 0x201F

// orientation: 2 = A, 1 = B, 0 = unknown (shfl fallback)
__device__ __forceinline__ int orient_pls32(unsigned lane) {
#if HAS_PLS32
    uv2 r = __builtin_amdgcn_permlane32_swap(lane, 1000u + lane, false, false);
    const bool lo = lane < 32;
    unsigned ax = lo ? lane : (1000u + lane - 32u);
    unsigned ay = lo ? (lane + 32u) : (1000u + lane);
    unsigned bx = lo ? (1000u + lane + 32u) : lane;
    unsigned by = lo ? (1000u + lane) : (lane - 32u);
    if (__all(r.x == ax && r.y == ay)) return 2;
    if (__all(r.x == bx && r.y == by)) return 1;
#endif
    return 0;
}
__device__ __forceinline__ int orient_pls16(unsigned lane) {
#if HAS_PLS16
    uv2 r = __builtin_amdgcn_permlane16_swap(lane, 1000u + lane, false, false);
    const bool hi = (lane & 16u) != 0u;
    unsigned ax = hi ? (1000u + lane - 16u) : lane;
    unsigned ay = hi ? (1000u + lane) : (lane + 16u);
    unsigned bx = hi ? lane : (1000u + lane + 16u);
    unsigned by = hi ? (lane - 16u) : (1000u + lane);
    if (__all(r.x == ax && r.y == ay)) return 2;
    if (__all(r.x == bx && r.y == by)) return 1;
#endif
    return 0;
}

// ---------------------------------------------------------------------------
// Packed stage helpers
// ---------------------------------------------------------------------------
__device__ __forceinline__ void pk_mstage(f32x2& ar, f32x2& ai, f32x2& br, f32x2& bi,
                                          float m0, float m1, float m2, float m3,
                                          float m4, float m5, float m6, float m7) {
    f32x2 nar = m0 * ar - m1 * ai + m2 * br - m3 * bi;
    f32x2 nai = m0 * ai + m1 * ar + m2 * bi + m3 * br;
    f32x2 nbr = m4 * ar - m5 * ai + m6 * br - m7 * bi;
    f32x2 nbi = m4 * ai + m5 * ar + m6 * bi + m7 * br;
    ar = nar; ai = nai; br = nbr; bi = nbi;
}

template <class F>
__device__ __forceinline__ void pk_fetch_stage(f32x2 re[2][4], f32x2 im[2][4],
                                               float c0r, float c0i, float c1r, float c1i,
                                               F fetch) {
#pragma unroll
    for (int p = 0; p < 2; ++p)
#pragma unroll
        for (int l = 0; l < 4; ++l) {
            const f32x2 r = re[p][l], i = im[p][l];
            const f32x2 pr = fetch(r), pi = fetch(i);
            re[p][l] = c0r * r - c0i * i + c1r * pr - c1i * pi;
            im[p][l] = c0r * i + c0i * r + c1r * pi + c1i * pr;
        }
}

#if HAS_PLS32
__device__ __forceinline__ void pk_pls32_mstage(f32x2& fr, f32x2& fi, f32x2& gr, f32x2& gi,
                                                float m0, float m1, float m2, float m3,
                                                float m4, float m5, float m6, float m7,
                                                bool orientA) {
    uv2 rx = __builtin_amdgcn_permlane32_swap(__float_as_uint(fr.x), __float_as_uint(gr.x), false, false);
    uv2 ry = __builtin_amdgcn_permlane32_swap(__float_as_uint(fr.y), __float_as_uint(gr.y), false, false);
    uv2 ix = __builtin_amdgcn_permlane32_swap(__float_as_uint(fi.x), __float_as_uint(gi.x), false, false);
    uv2 iy = __builtin_amdgcn_permlane32_swap(__float_as_uint(fi.y), __float_as_uint(gi.y), false, false);
    f32x2 pxr = {__uint_as_float(rx.x), __uint_as_float(ry.x)};
    f32x2 pyr = {__uint_as_float(rx.y), __uint_as_float(ry.y)};
    f32x2 pxi = {__uint_as_float(ix.x), __uint_as_float(iy.x)};
    f32x2 pyi = {__uint_as_float(ix.y), __uint_as_float(iy.y)};
    f32x2 A1r, A1i, A2r, A2i;
    if (orientA) {
        A1r = m0 * pxr - m1 * pxi + m2 * pyr - m3 * pyi;
        A1i = m0 * pxi + m1 * pxr + m2 * pyi + m3 * pyr;
        A2r = m4 * pxr - m5 * pxi + m6 * pyr - m7 * pyi;
        A2i = m4 * pxi + m5 * pxr + m6 * pyi + m7 * pyr;
    } else {
        A1r = m6 * pxr - m7 * pxi + m4 * pyr - m5 * pyi;
        A1i = m6 * pxi + m7 * pxr + m4 * pyi + m5 * pyr;
        A2r = m2 * pxr - m3 * pxi + m0 * pyr - m1 * pyi;
        A2i = m2 * pxi + m3 * pxr + m0 * pyi + m1 * pyr;
    }
    uv2 ox = __builtin_amdgcn_permlane32_swap(__float_as_uint(A1r.x), __float_as_uint(A2r.x), false, false);
    uv2 oy = __builtin_amdgcn_permlane32_swap(__float_as_uint(A1r.y), __float_as_uint(A2r.y), false, false);
    uv2 px = __builtin_amdgcn_permlane32_swap(__float_as_uint(A1i.x), __float_as_uint(A2i.x), false, false);
    uv2 py = __builtin_amdgcn_permlane32_swap(__float_as_uint(A1i.y), __float_as_uint(A2i.y), false, false);
    fr = (f32x2){__uint_as_float(ox.x), __uint_as_float(oy.x)};
    gr = (f32x2){__uint_as_float(ox.y), __uint_as_float(oy.y)};
    fi = (f32x2){__uint_as_float(px.x), __uint_as_float(py.x)};
    gi = (f32x2){__uint_as_float(px.y), __uint_as_float(py.y)};
}
#endif
#if HAS_PLS16
__device__ __forceinline__ void pk_pls16_mstage(f32x2& fr, f32x2& fi, f32x2& gr, f32x2& gi,
                                                float m0, float m1, float m2, float m3,
                                                float m4, float m5, float m6, float m7,
                                                bool orientA) {
    uv2 rx = __builtin_amdgcn_permlane16_swap(__float_as_uint(fr.x), __float_as_uint(gr.x), false, false);
    uv2 ry = __builtin_amdgcn_permlane16_swap(__float_as_uint(fr.y), __float_as_uint(gr.y), false, false);
    uv2 ix = __builtin_amdgcn_permlane16_swap(__float_as_uint(fi.x), __float_as_uint(gi.x), false, false);
    uv2 iy = __builtin_amdgcn_permlane16_swap(__float_as_uint(fi.y), __float_as_uint(gi.y), false, false);
    f32x2 pxr = {__uint_as_float(rx.x), __uint_as_float(ry.x)};
    f32x2 pyr = {__uint_as_float(rx.y), __uint_as_float(ry.y)};
    f32x2 pxi = {__uint_as_float(ix.x), __uint_as_float(iy.x)};
    f32x2 pyi = {__uint_as_float(ix.y), __uint_as_float(iy.y)};
    f32x2 A1r, A1i, A2r, A2i;
    if (orientA) {
        A1r = m0 * pxr - m1 * pxi + m2 * pyr - m3 * pyi;
        A1i = m0 * pxi + m1 * pxr + m2 * pyi + m3 * pyr;
        A2r = m4 * pxr - m5 * pxi + m6 * pyr - m7 * pyi;
        A2i = m4 * pxi + m5 * pxr + m6 * pyi + m7 * pyr;
    } else {
        A1r = m6 * pxr - m7 * pxi + m4 * pyr - m5 * pyi;
        A1i = m6 * pxi + m7 * pxr + m4 * pyi + m5 * pyr;
        A2r = m2 * pxr - m3 * pxi + m0 * pyr - m1 * pyi;
        A2i = m2 * pxi + m3 * pxr + m0 * pyi + m1 * pyr;
    }
    uv2 ox = __builtin_amdgcn_permlane16_swap(__float_as_uint(A1r.x), __float_as_uint(A2r.x), false, false);
    uv2 oy = __builtin_amdgcn_permlane16_swap(__float_as_uint(A1r.y), __float_as_uint(A2r.y), false, false);
    uv2 px = __builtin_amdgcn_permlane16_swap(__float_as_uint(A1i.x), __float_as_uint(A2i.x), false, false);
    uv2 py = __builtin_amdgcn_permlane16_swap(__float_as_uint(A1i.y), __float_as_uint(A2i.y), false, false);
    fr = (f32x2){__uint_as_float(ox.x), __uint_as_float(oy.x)};
    gr = (f32x2){__uint_as_float(ox.y), __uint_as_float(oy.y)};
    fi = (f32x2){__uint_as_float(px.x), __uint_as_float(py.x)};
    gi = (f32x2){__uint_as_float(px.y), __uint_as_float(py.y)};
}
#endif

// ---------------------------------------------------------------------------
// Row helpers: raw load (kept in load regs), pack, 10-stage compute, store.
// ---------------------------------------------------------------------------
__device__ __forceinline__ void load_raw(const float* __restrict__ xr, int lane,
                                         f32x4 raw[2][4]) {
#pragma unroll
    for (int p = 0; p < 2; ++p) {
        raw[p][0] = *(const f32x4*)(xr + (2 * p + 0) * 256 + lane * 4);          // reA
        raw[p][1] = *(const f32x4*)(xr + DIMQ + (2 * p + 0) * 256 + lane * 4);   // imA
        raw[p][2] = *(const f32x4*)(xr + (2 * p + 1) * 256 + lane * 4);          // reB
        raw[p][3] = *(const f32x4*)(xr + DIMQ + (2 * p + 1) * 256 + lane * 4);   // imB
    }
}

__device__ __forceinline__ void pack_raw(const f32x4 raw[2][4],
                                         f32x2 Pre[2][4], f32x2 Pim[2][4]) {
#pragma unroll
    for (int p = 0; p < 2; ++p)
#pragma unroll
        for (int l = 0; l < 4; ++l) {
            Pre[p][l] = (f32x2){raw[p][0][l], raw[p][2][l]};
            Pim[p][l] = (f32x2){raw[p][1][l], raw[p][3][l]};
        }
}

__device__ __forceinline__ void store_state(float* __restrict__ orow, int lane,
                                            const f32x2 Pre[2][4], const f32x2 Pim[2][4]) {
#pragma unroll
    for (int p = 0; p < 2; ++p)
#pragma unroll
        for (int c = 0; c < 2; ++c) {
            const int j = 2 * p + c;
            f32x4 r4 = {Pre[p][0][c], Pre[p][1][c], Pre[p][2][c], Pre[p][3][c]};
            f32x4 i4 = {Pim[p][0][c], Pim[p][1][c], Pim[p][2][c], Pim[p][3][c]};
            __builtin_nontemporal_store(r4, (f32x4*)(orow + j * 256 + lane * 4));
            __builtin_nontemporal_store(i4, (f32x4*)(orow + DIMQ + j * 256 + lane * 4));
        }
}

template <bool USE_WS>
__device__ __forceinline__ void apply_stages(f32x2 Pre[2][4], f32x2 Pim[2][4],
                                             const float* __restrict__ Mtab,
                                             const float* __restrict__ Ml,
                                             int lane, int o16, int o32) {
    float m0, m1, m2, m3, m4, m5, m6, m7;
#define LOADM(s_) do {                                                     \
    const float* _mp = USE_WS ? (Mtab + (s_) * 8) : (Ml + (s_) * 8);       \
    m0 = _mp[0]; m1 = _mp[1]; m2 = _mp[2]; m3 = _mp[3];                    \
    m4 = _mp[4]; m5 = _mp[5]; m6 = _mp[6]; m7 = _mp[7];                    \
} while (0)
#define SELC(maskbit) \
    const bool hb = (lane & (maskbit)) != 0;                               \
    const float c0r = hb ? m6 : m0, c0i = hb ? m7 : m1;                    \
    const float c1r = hb ? m4 : m2, c1i = hb ? m5 : m3;

    // stage 0: element bit0 (register pairs l^1)
    LOADM(0);
#pragma unroll
    for (int p = 0; p < 2; ++p) {
        pk_mstage(Pre[p][0], Pim[p][0], Pre[p][1], Pim[p][1], m0, m1, m2, m3, m4, m5, m6, m7);
        pk_mstage(Pre[p][2], Pim[p][2], Pre[p][3], Pim[p][3], m0, m1, m2, m3, m4, m5, m6, m7);
    }
    // stage 1: element bit1 (register pairs l^2)
    LOADM(1);
#pragma unroll
    for (int p = 0; p < 2; ++p) {
        pk_mstage(Pre[p][0], Pim[p][0], Pre[p][2], Pim[p][2], m0, m1, m2, m3, m4, m5, m6, m7);
        pk_mstage(Pre[p][1], Pim[p][1], Pre[p][3], Pim[p][3], m0, m1, m2, m3, m4, m5, m6, m7);
    }
    // stage 2: lane mask 1 (DPP)
    {
        LOADM(2);
        SELC(1);
        pk_fetch_stage(Pre, Pim, c0r, c0i, c1r, c1i,
                       [](f32x2 v) { return pk_dpp<DPP_XOR1>(v); });
    }
    // stage 3: lane mask 2 (DPP)
    {
        LOADM(3);
        SELC(2);
        pk_fetch_stage(Pre, Pim, c0r, c0i, c1r, c1i,
                       [](f32x2 v) { return pk_dpp<DPP_XOR2>(v); });
    }
    // stage 4: lane mask 4 (ds_swizzle)
    {
        LOADM(4);
        SELC(4);
        pk_fetch_stage(Pre, Pim, c0r, c0i, c1r, c1i,
                       [](f32x2 v) { return pk_swz<SWZ_XOR4>(v); });
    }
    // stage 5: lane mask 8 (ds_swizzle)
    {
        LOADM(5);
        SELC(8);
        pk_fetch_stage(Pre, Pim, c0r, c0i, c1r, c1i,
                       [](f32x2 v) { return pk_swz<SWZ_XOR8>(v); });
    }
    // stage 6: lane mask 16 (permlane16_swap)
    {
        LOADM(6);
#if HAS_PLS16
        if (o16 != 0) {
            const bool oA = (o16 == 2);
#pragma unroll
            for (int p = 0; p < 2; ++p) {
                pk_pls16_mstage(Pre[p][0], Pim[p][0], Pre[p][1], Pim[p][1], m0, m1, m2, m3, m4, m5, m6, m7, oA);
                pk_pls16_mstage(Pre[p][2], Pim[p][2], Pre[p][3], Pim[p][3], m0, m1, m2, m3, m4, m5, m6, m7, oA);
            }
        } else
#endif
        {
            SELC(16);
            pk_fetch_stage(Pre, Pim, c0r, c0i, c1r, c1i,
                           [](f32x2 v) { return pk_shfl_xor(v, 16); });
        }
    }
    // stage 7: lane mask 32 (permlane32_swap)
    {
        LOADM(7);
#if HAS_PLS32
        if (o32 != 0) {
            const bool oA = (o32 == 2);
#pragma unroll
            for (int p = 0; p < 2; ++p) {
                pk_pls32_mstage(Pre[p][0], Pim[p][0], Pre[p][1], Pim[p][1], m0, m1, m2, m3, m4, m5, m6, m7, oA);
                pk_pls32_mstage(Pre[p][2], Pim[p][2], Pre[p][3], Pim[p][3], m0, m1, m2, m3, m4, m5, m6, m7, oA);
            }
        } else
#endif
        {
            SELC(32);
            pk_fetch_stage(Pre, Pim, c0r, c0i, c1r, c1i,
                           [](f32x2 v) { return pk_shfl_xor(v, 32); });
        }
    }
    // stage 8: element bit8 (j^1 = intra-pack), split consts + comp swap
    {
        LOADM(8);
        const f32x2 csr = {m0, m6}, csi = {m1, m7};
        const f32x2 cor = {m2, m4}, coi = {m3, m5};
#pragma unroll
        for (int p = 0; p < 2; ++p)
#pragma unroll
            for (int l = 0; l < 4; ++l) {
                const f32x2 r = Pre[p][l], i = Pim[p][l];
                const f32x2 Sr = pk_swap(r), Si = pk_swap(i);
                Pre[p][l] = csr * r - csi * i + cor * Sr - coi * Si;
                Pim[p][l] = csr * i + csi * r + cor * Si + coi * Sr;
            }
    }
    // stage 9: element bit9 (j^2 = across packs)
    LOADM(9);
#pragma unroll
    for (int l = 0; l < 4; ++l)
        pk_mstage(Pre[0][l], Pim[0][l], Pre[1][l], Pim[1][l], m0, m1, m2, m3, m4, m5, m6, m7);
#undef LOADM
#undef SELC
}

// ---------------------------------------------------------------------------
// Main kernel: one wave per TWO rows; row1's raw loads issued before row0's
// compute so their HBM latency hides under it. __launch_bounds__(256,6)
// caps VGPR (~85) so occupancy stays >= 6 waves/SIMD.
// ---------------------------------------------------------------------------
template <bool USE_WS>
__global__ __launch_bounds__(256, 6)
void qlayer_fused(const float* __restrict__ x, const float* __restrict__ Mtab,
                  const float* __restrict__ alphas, const float* __restrict__ betas,
                  const float* __restrict__ thetas, const float* __restrict__ phis,
                  float* __restrict__ out) {
    const int lane = threadIdx.x & 63;
    const int wv   = threadIdx.x >> 6;
    const int gw   = blockIdx.x * 4 + wv;   // global wave id, [0, 8192)
    const int row0 = gw * 2;

    const int o16 = orient_pls16((unsigned)lane);
    const int o32 = orient_pls32((unsigned)lane);

    const float* __restrict__ xr0 = x + (size_t)row0 * (2 * DIMQ);
    const float* __restrict__ xr1 = xr0 + 2 * DIMQ;
    float* __restrict__ or0       = out + (size_t)row0 * (2 * DIMQ);
    float* __restrict__ or1       = or0 + 2 * DIMQ;

    // Fallback matrices (identical in all lanes) when no workspace.
    float Ml[NQ * 8];
    if (!USE_WS) {
#pragma unroll
        for (int b = 0; b < NQ; ++b) {
            const int q = NQ - 1 - b;
            float sa, ca, sb, cb, st, ct, sp, cp;
            sincosf(alphas[q], &sa, &ca);
            sincosf(betas[q],  &sb, &cb);
            sincosf(thetas[q], &st, &ct);
            sincosf(phis[q],   &sp, &cp);
            const float2 u = make_float2(ca, sa), v = make_float2(cb, sb), p2 = make_float2(cp, sp);
            const float2 tm1  = make_float2(ct - 1.f, st);
            const float2 itp1 = make_float2(-st, ct + 1.f);
            const float2 omt  = make_float2(1.f - ct, -st);
            float2 m00 = cmulc(cmulc(p2, u), tm1);
            float2 m01 = cmulc(cmulc(p2, v), itp1);
            float2 m10 = cmulc(u, itp1);
            float2 m11 = cmulc(v, omt);
            Ml[b * 8 + 0] = m00.x * .5f; Ml[b * 8 + 1] = m00.y * .5f;
            Ml[b * 8 + 2] = m01.x * .5f; Ml[b * 8 + 3] = m01.y * .5f;
            Ml[b * 8 + 4] = m10.x * .5f; Ml[b * 8 + 5] = m10.y * .5f;
            Ml[b * 8 + 6] = m11.x * .5f; Ml[b * 8 + 7] = m11.y * .5f;
        }
    }

    // ---- software pipeline: load0 -> pack0 -> load1(issue) -> compute0 ->
    //      store0 -> pack1(waits) -> compute1 -> store1
    f32x4 raw0[2][4];
    load_raw(xr0, lane, raw0);
    f32x2 Pre[2][4], Pim[2][4];
    pack_raw(raw0, Pre, Pim);          // waits on row0's loads only

    f32x4 raw1[2][4];
    load_raw(xr1, lane, raw1);         // issued now, in flight during compute0

    apply_stages<USE_WS>(Pre, Pim, Mtab, Ml, lane, o16, o32);
    store_state(or0, lane, Pre, Pim);

    pack_raw(raw1, Pre, Pim);          // vmcnt wait on row1's loads
    apply_stages<USE_WS>(Pre, Pim, Mtab, Ml, lane, o16, o32);
    store_state(or1, lane, Pre, Pim);
}

extern "C" void kernel_launch(void* const* d_in, const int* in_sizes, int n_in,
                              void* d_out, int out_size, void* d_ws, size_t ws_size,
                              hipStream_t stream) {
    const float* x      = (const float*)d_in[0];
    const float* alphas = (const float*)d_in[1];
    const float* betas  = (const float*)d_in[2];
    const float* thetas = (const float*)d_in[3];
    const float* phis   = (const float*)d_in[4];
    float* out = (float*)d_out;

    const int blocks = BATCH_ROWS / 8;  // 4 waves/block, 2 rows/wave = 2048

    if (ws_size >= NQ * 8 * sizeof(float)) {
        float* M = (float*)d_ws;
        qmat_precompute<<<1, 64, 0, stream>>>(alphas, betas, thetas, phis, M);
        qlayer_fused<true><<<blocks, 256, 0, stream>>>(x, M, alphas, betas, thetas, phis, out);
    } else {
        qlayer_fused<false><<<blocks, 256, 0, stream>>>(x, nullptr, alphas, betas, thetas, phis, out);
    }
}

// Round 9
// 66.621 us; speedup vs baseline: 1.7563x; 1.7563x over previous
//
#include <hip/hip_runtime.h>
#include <math.h>

#define NQ   10
#define DIMQ 1024
#define BATCH_ROWS 16384

typedef unsigned uv2 __attribute__((ext_vector_type(2)));
typedef float f32x2 __attribute__((ext_vector_type(2)));
typedef float f32x4 __attribute__((ext_vector_type(4)));

#if __has_builtin(__builtin_amdgcn_permlane32_swap)
#define HAS_PLS32 1
#else
#define HAS_PLS32 0
#endif
#if __has_builtin(__builtin_amdgcn_permlane16_swap)
#define HAS_PLS16 1
#else
#define HAS_PLS16 0
#endif

// ---------------------------------------------------------------------------
// Precompute: one fused 2x2 complex matrix per qubit (validated R6/R7).
//   M_k = D(phi)*BS*D(theta)*BS*D(alpha,beta)
//   = 0.5*[[p*u*(t-1), p*v*i(t+1)], [u*i(t+1), v*(1-t)]]
// ---------------------------------------------------------------------------
__device__ __forceinline__ float2 cmulc(float2 a, float2 b) {
    return make_float2(a.x * b.x - a.y * b.y, a.x * b.y + a.y * b.x);
}

__global__ void qmat_precompute(const float* __restrict__ alphas,
                                const float* __restrict__ betas,
                                const float* __restrict__ thetas,
                                const float* __restrict__ phis,
                                float* __restrict__ M) {
    const int b = threadIdx.x;
    if (b >= NQ) return;
    const int q = NQ - 1 - b;
    float sa, ca, sb, cb, st, ct, sp, cp;
    sincosf(alphas[q], &sa, &ca);
    sincosf(betas[q],  &sb, &cb);
    sincosf(thetas[q], &st, &ct);
    sincosf(phis[q],   &sp, &cp);
    const float2 u = make_float2(ca, sa), v = make_float2(cb, sb), p = make_float2(cp, sp);
    const float2 tm1  = make_float2(ct - 1.f, st);
    const float2 itp1 = make_float2(-st, ct + 1.f);
    const float2 omt  = make_float2(1.f - ct, -st);
    float2 m00 = cmulc(cmulc(p, u), tm1);
    float2 m01 = cmulc(cmulc(p, v), itp1);
    float2 m10 = cmulc(u, itp1);
    float2 m11 = cmulc(v, omt);
    const float s = 0.5f;
    M[b * 8 + 0] = m00.x * s; M[b * 8 + 1] = m00.y * s;
    M[b * 8 + 2] = m01.x * s; M[b * 8 + 3] = m01.y * s;
    M[b * 8 + 4] = m10.x * s; M[b * 8 + 5] = m10.y * s;
    M[b * 8 + 6] = m11.x * s; M[b * 8 + 7] = m11.y * s;
}

// ---------------------------------------------------------------------------
// Cross-lane primitives (scalar + packed wrappers)
// ---------------------------------------------------------------------------
template <int CTRL>
__device__ __forceinline__ float dpp_mov(float x) {
    return __int_as_float(
        __builtin_amdgcn_update_dpp(0, __float_as_int(x), CTRL, 0xF, 0xF, true));
}
template <int PAT>
__device__ __forceinline__ float ds_swz(float x) {
    return __int_as_float(__builtin_amdgcn_ds_swizzle(__float_as_int(x), PAT));
}
template <int CTRL>
__device__ __forceinline__ f32x2 pk_dpp(f32x2 v) {
    return (f32x2){dpp_mov<CTRL>(v.x), dpp_mov<CTRL>(v.y)};
}
template <int PAT>
__device__ __forceinline__ f32x2 pk_swz(f32x2 v) {
    return (f32x2){ds_swz<PAT>(v.x), ds_swz<PAT>(v.y)};
}
__device__ __forceinline__ f32x2 pk_shfl_xor(f32x2 v, int m) {
    return (f32x2){__shfl_xor(v.x, m, 64), __shfl_xor(v.y, m, 64)};
}
__device__ __forceinline__ f32x2 pk_swap(f32x2 v) { return (f32x2){v.y, v.x}; }

#define DPP_XOR1 0xB1
#define DPP_XOR2 0x4E
#define SWZ_XOR4 0x101F
#define SWZ_XOR8 0x201F

// orientation: 2 = A, 1 = B, 0 = unknown (shfl fallback)
__device__ __forceinline__ int orient_pls32(unsigned lane) {
#if HAS_PLS32
    uv2 r = __builtin_amdgcn_permlane32_swap(lane, 1000u + lane, false, false);
    const bool lo = lane < 32;
    unsigned ax = lo ? lane : (1000u + lane - 32u);
    unsigned ay = lo ? (lane + 32u) : (1000u + lane);
    unsigned bx = lo ? (1000u + lane + 32u) : lane;
    unsigned by = lo ? (1000u + lane) : (lane - 32u);
    if (__all(r.x == ax && r.y == ay)) return 2;
    if (__all(r.x == bx && r.y == by)) return 1;
#endif
    return 0;
}
__device__ __forceinline__ int orient_pls16(unsigned lane) {
#if HAS_PLS16
    uv2 r = __builtin_amdgcn_permlane16_swap(lane, 1000u + lane, false, false);
    const bool hi = (lane & 16u) != 0u;
    unsigned ax = hi ? (1000u + lane - 16u) : lane;
    unsigned ay = hi ? (1000u + lane) : (lane + 16u);
    unsigned bx = hi ? lane : (1000u + lane + 16u);
    unsigned by = hi ? (lane - 16u) : (1000u + lane);
    if (__all(r.x == ax && r.y == ay)) return 2;
    if (__all(r.x == bx && r.y == by)) return 1;
#endif
    return 0;
}

// ---------------------------------------------------------------------------
// Packed stage helpers
// ---------------------------------------------------------------------------
__device__ __forceinline__ void pk_mstage(f32x2& ar, f32x2& ai, f32x2& br, f32x2& bi,
                                          float m0, float m1, float m2, float m3,
                                          float m4, float m5, float m6, float m7) {
    f32x2 nar = m0 * ar - m1 * ai + m2 * br - m3 * bi;
    f32x2 nai = m0 * ai + m1 * ar + m2 * bi + m3 * br;
    f32x2 nbr = m4 * ar - m5 * ai + m6 * br - m7 * bi;
    f32x2 nbi = m4 * ai + m5 * ar + m6 * bi + m7 * br;
    ar = nar; ai = nai; br = nbr; bi = nbi;
}

template <class F>
__device__ __forceinline__ void pk_fetch_stage(f32x2 re[2][4], f32x2 im[2][4],
                                               float c0r, float c0i, float c1r, float c1i,
                                               F fetch) {
#pragma unroll
    for (int p = 0; p < 2; ++p)
#pragma unroll
        for (int l = 0; l < 4; ++l) {
            const f32x2 r = re[p][l], i = im[p][l];
            const f32x2 pr = fetch(r), pi = fetch(i);
            re[p][l] = c0r * r - c0i * i + c1r * pr - c1i * pi;
            im[p][l] = c0r * i + c0i * r + c1r * pi + c1i * pr;
        }
}

#if HAS_PLS32
__device__ __forceinline__ void pk_pls32_mstage(f32x2& fr, f32x2& fi, f32x2& gr, f32x2& gi,
                                                float m0, float m1, float m2, float m3,
                                                float m4, float m5, float m6, float m7,
                                                bool orientA) {
    uv2 rx = __builtin_amdgcn_permlane32_swap(__float_as_uint(fr.x), __float_as_uint(gr.x), false, false);
    uv2 ry = __builtin_amdgcn_permlane32_swap(__float_as_uint(fr.y), __float_as_uint(gr.y), false, false);
    uv2 ix = __builtin_amdgcn_permlane32_swap(__float_as_uint(fi.x), __float_as_uint(gi.x), false, false);
    uv2 iy = __builtin_amdgcn_permlane32_swap(__float_as_uint(fi.y), __float_as_uint(gi.y), false, false);
    f32x2 pxr = {__uint_as_float(rx.x), __uint_as_float(ry.x)};
    f32x2 pyr = {__uint_as_float(rx.y), __uint_as_float(ry.y)};
    f32x2 pxi = {__uint_as_float(ix.x), __uint_as_float(iy.x)};
    f32x2 pyi = {__uint_as_float(ix.y), __uint_as_float(iy.y)};
    f32x2 A1r, A1i, A2r, A2i;
    if (orientA) {
        A1r = m0 * pxr - m1 * pxi + m2 * pyr - m3 * pyi;
        A1i = m0 * pxi + m1 * pxr + m2 * pyi + m3 * pyr;
        A2r = m4 * pxr - m5 * pxi + m6 * pyr - m7 * pyi;
        A2i = m4 * pxi + m5 * pxr + m6 * pyi + m7 * pyr;
    } else {
        A1r = m6 * pxr - m7 * pxi + m4 * pyr - m5 * pyi;
        A1i = m6 * pxi + m7 * pxr + m4 * pyi + m5 * pyr;
        A2r = m2 * pxr - m3 * pxi + m0 * pyr - m1 * pyi;
        A2i = m2 * pxi + m3 * pxr + m0 * pyi + m1 * pyr;
    }
    uv2 ox = __builtin_amdgcn_permlane32_swap(__float_as_uint(A1r.x), __float_as_uint(A2r.x), false, false);
    uv2 oy = __builtin_amdgcn_permlane32_swap(__float_as_uint(A1r.y), __float_as_uint(A2r.y), false, false);
    uv2 px = __builtin_amdgcn_permlane32_swap(__float_as_uint(A1i.x), __float_as_uint(A2i.x), false, false);
    uv2 py = __builtin_amdgcn_permlane32_swap(__float_as_uint(A1i.y), __float_as_uint(A2i.y), false, false);
    fr = (f32x2){__uint_as_float(ox.x), __uint_as_float(oy.x)};
    gr = (f32x2){__uint_as_float(ox.y), __uint_as_float(oy.y)};
    fi = (f32x2){__uint_as_float(px.x), __uint_as_float(py.x)};
    gi = (f32x2){__uint_as_float(px.y), __uint_as_float(py.y)};
}
#endif
#if HAS_PLS16
__device__ __forceinline__ void pk_pls16_mstage(f32x2& fr, f32x2& fi, f32x2& gr, f32x2& gi,
                                                float m0, float m1, float m2, float m3,
                                                float m4, float m5, float m6, float m7,
                                                bool orientA) {
    uv2 rx = __builtin_amdgcn_permlane16_swap(__float_as_uint(fr.x), __float_as_uint(gr.x), false, false);
    uv2 ry = __builtin_amdgcn_permlane16_swap(__float_as_uint(fr.y), __float_as_uint(gr.y), false, false);
    uv2 ix = __builtin_amdgcn_permlane16_swap(__float_as_uint(fi.x), __float_as_uint(gi.x), false, false);
    uv2 iy = __builtin_amdgcn_permlane16_swap(__float_as_uint(fi.y), __float_as_uint(gi.y), false, false);
    f32x2 pxr = {__uint_as_float(rx.x), __uint_as_float(ry.x)};
    f32x2 pyr = {__uint_as_float(rx.y), __uint_as_float(ry.y)};
    f32x2 pxi = {__uint_as_float(ix.x), __uint_as_float(iy.x)};
    f32x2 pyi = {__uint_as_float(ix.y), __uint_as_float(iy.y)};
    f32x2 A1r, A1i, A2r, A2i;
    if (orientA) {
        A1r = m0 * pxr - m1 * pxi + m2 * pyr - m3 * pyi;
        A1i = m0 * pxi + m1 * pxr + m2 * pyi + m3 * pyr;
        A2r = m4 * pxr - m5 * pxi + m6 * pyr - m7 * pyi;
        A2i = m4 * pxi + m5 * pxr + m6 * pyi + m7 * pyr;
    } else {
        A1r = m6 * pxr - m7 * pxi + m4 * pyr - m5 * pyi;
        A1i = m6 * pxi + m7 * pxr + m4 * pyi + m5 * pyr;
        A2r = m2 * pxr - m3 * pxi + m0 * pyr - m1 * pyi;
        A2i = m2 * pxi + m3 * pxr + m0 * pyi + m1 * pyr;
    }
    uv2 ox = __builtin_amdgcn_permlane16_swap(__float_as_uint(A1r.x), __float_as_uint(A2r.x), false, false);
    uv2 oy = __builtin_amdgcn_permlane16_swap(__float_as_uint(A1r.y), __float_as_uint(A2r.y), false, false);
    uv2 px = __builtin_amdgcn_permlane16_swap(__float_as_uint(A1i.x), __float_as_uint(A2i.x), false, false);
    uv2 py = __builtin_amdgcn_permlane16_swap(__float_as_uint(A1i.y), __float_as_uint(A2i.y), false, false);
    fr = (f32x2){__uint_as_float(ox.x), __uint_as_float(oy.x)};
    gr = (f32x2){__uint_as_float(ox.y), __uint_as_float(oy.y)};
    fi = (f32x2){__uint_as_float(px.x), __uint_as_float(py.x)};
    gi = (f32x2){__uint_as_float(px.y), __uint_as_float(py.y)};
}
#endif

// ---------------------------------------------------------------------------
// Row helpers
// ---------------------------------------------------------------------------
__device__ __forceinline__ void load_raw(const float* __restrict__ xr, int lane,
                                         f32x4 raw[2][4]) {
#pragma unroll
    for (int p = 0; p < 2; ++p) {
        raw[p][0] = *(const f32x4*)(xr + (2 * p + 0) * 256 + lane * 4);          // reA
        raw[p][1] = *(const f32x4*)(xr + DIMQ + (2 * p + 0) * 256 + lane * 4);   // imA
        raw[p][2] = *(const f32x4*)(xr + (2 * p + 1) * 256 + lane * 4);          // reB
        raw[p][3] = *(const f32x4*)(xr + DIMQ + (2 * p + 1) * 256 + lane * 4);   // imB
    }
}

__device__ __forceinline__ void pack_raw(const f32x4 raw[2][4],
                                         f32x2 Pre[2][4], f32x2 Pim[2][4]) {
#pragma unroll
    for (int p = 0; p < 2; ++p)
#pragma unroll
        for (int l = 0; l < 4; ++l) {
            Pre[p][l] = (f32x2){raw[p][0][l], raw[p][2][l]};
            Pim[p][l] = (f32x2){raw[p][1][l], raw[p][3][l]};
        }
}

// Plain (cached) stores — R2 evidence: fastest round used plain stores.
__device__ __forceinline__ void store_state(float* __restrict__ orow, int lane,
                                            const f32x2 Pre[2][4], const f32x2 Pim[2][4]) {
#pragma unroll
    for (int p = 0; p < 2; ++p)
#pragma unroll
        for (int c = 0; c < 2; ++c) {
            const int j = 2 * p + c;
            f32x4 r4 = {Pre[p][0][c], Pre[p][1][c], Pre[p][2][c], Pre[p][3][c]};
            f32x4 i4 = {Pim[p][0][c], Pim[p][1][c], Pim[p][2][c], Pim[p][3][c]};
            *(f32x4*)(orow + j * 256 + lane * 4) = r4;
            *(f32x4*)(orow + DIMQ + j * 256 + lane * 4) = i4;
        }
}

template <bool USE_WS>
__device__ __forceinline__ void apply_stages(f32x2 Pre[2][4], f32x2 Pim[2][4],
                                             const float* __restrict__ Mtab,
                                             const float* __restrict__ Ml,
                                             int lane, int o16, int o32) {
    float m0, m1, m2, m3, m4, m5, m6, m7;
#define LOADM(s_) do {                                                     \
    const float* _mp = USE_WS ? (Mtab + (s_) * 8) : (Ml + (s_) * 8);       \
    m0 = _mp[0]; m1 = _mp[1]; m2 = _mp[2]; m3 = _mp[3];                    \
    m4 = _mp[4]; m5 = _mp[5]; m6 = _mp[6]; m7 = _mp[7];                    \
} while (0)
#define SELC(maskbit) \
    const bool hb = (lane & (maskbit)) != 0;                               \
    const float c0r = hb ? m6 : m0, c0i = hb ? m7 : m1;                    \
    const float c1r = hb ? m4 : m2, c1i = hb ? m5 : m3;

    // stage 0: element bit0 (register pairs l^1)
    LOADM(0);
#pragma unroll
    for (int p = 0; p < 2; ++p) {
        pk_mstage(Pre[p][0], Pim[p][0], Pre[p][1], Pim[p][1], m0, m1, m2, m3, m4, m5, m6, m7);
        pk_mstage(Pre[p][2], Pim[p][2], Pre[p][3], Pim[p][3], m0, m1, m2, m3, m4, m5, m6, m7);
    }
    // stage 1: element bit1 (register pairs l^2)
    LOADM(1);
#pragma unroll
    for (int p = 0; p < 2; ++p) {
        pk_mstage(Pre[p][0], Pim[p][0], Pre[p][2], Pim[p][2], m0, m1, m2, m3, m4, m5, m6, m7);
        pk_mstage(Pre[p][1], Pim[p][1], Pre[p][3], Pim[p][3], m0, m1, m2, m3, m4, m5, m6, m7);
    }
    // stage 2: lane mask 1 (DPP)
    {
        LOADM(2);
        SELC(1);
        pk_fetch_stage(Pre, Pim, c0r, c0i, c1r, c1i,
                       [](f32x2 v) { return pk_dpp<DPP_XOR1>(v); });
    }
    // stage 3: lane mask 2 (DPP)
    {
        LOADM(3);
        SELC(2);
        pk_fetch_stage(Pre, Pim, c0r, c0i, c1r, c1i,
                       [](f32x2 v) { return pk_dpp<DPP_XOR2>(v); });
    }
    // stage 4: lane mask 4 (ds_swizzle)
    {
        LOADM(4);
        SELC(4);
        pk_fetch_stage(Pre, Pim, c0r, c0i, c1r, c1i,
                       [](f32x2 v) { return pk_swz<SWZ_XOR4>(v); });
    }
    // stage 5: lane mask 8 (ds_swizzle)
    {
        LOADM(5);
        SELC(8);
        pk_fetch_stage(Pre, Pim, c0r, c0i, c1r, c1i,
                       [](f32x2 v) { return pk_swz<SWZ_XOR8>(v); });
    }
    // stage 6: lane mask 16 (permlane16_swap)
    {
        LOADM(6);
#if HAS_PLS16
        if (o16 != 0) {
            const bool oA = (o16 == 2);
#pragma unroll
            for (int p = 0; p < 2; ++p) {
                pk_pls16_mstage(Pre[p][0], Pim[p][0], Pre[p][1], Pim[p][1], m0, m1, m2, m3, m4, m5, m6, m7, oA);
                pk_pls16_mstage(Pre[p][2], Pim[p][2], Pre[p][3], Pim[p][3], m0, m1, m2, m3, m4, m5, m6, m7, oA);
            }
        } else
#endif
        {
            SELC(16);
            pk_fetch_stage(Pre, Pim, c0r, c0i, c1r, c1i,
                           [](f32x2 v) { return pk_shfl_xor(v, 16); });
        }
    }
    // stage 7: lane mask 32 (permlane32_swap)
    {
        LOADM(7);
#if HAS_PLS32
        if (o32 != 0) {
            const bool oA = (o32 == 2);
#pragma unroll
            for (int p = 0; p < 2; ++p) {
                pk_pls32_mstage(Pre[p][0], Pim[p][0], Pre[p][1], Pim[p][1], m0, m1, m2, m3, m4, m5, m6, m7, oA);
                pk_pls32_mstage(Pre[p][2], Pim[p][2], Pre[p][3], Pim[p][3], m0, m1, m2, m3, m4, m5, m6, m7, oA);
            }
        } else
#endif
        {
            SELC(32);
            pk_fetch_stage(Pre, Pim, c0r, c0i, c1r, c1i,
                           [](f32x2 v) { return pk_shfl_xor(v, 32); });
        }
    }
    // stage 8: element bit8 (j^1 = intra-pack), split consts + comp swap
    {
        LOADM(8);
        const f32x2 csr = {m0, m6}, csi = {m1, m7};
        const f32x2 cor = {m2, m4}, coi = {m3, m5};
#pragma unroll
        for (int p = 0; p < 2; ++p)
#pragma unroll
            for (int l = 0; l < 4; ++l) {
                const f32x2 r = Pre[p][l], i = Pim[p][l];
                const f32x2 Sr = pk_swap(r), Si = pk_swap(i);
                Pre[p][l] = csr * r - csi * i + cor * Sr - coi * Si;
                Pim[p][l] = csr * i + csi * r + cor * Si + coi * Sr;
            }
    }
    // stage 9: element bit9 (j^2 = across packs)
    LOADM(9);
#pragma unroll
    for (int l = 0; l < 4; ++l)
        pk_mstage(Pre[0][l], Pim[0][l], Pre[1][l], Pim[1][l], m0, m1, m2, m3, m4, m5, m6, m7);
#undef LOADM
#undef SELC
}

// ---------------------------------------------------------------------------
// Main kernel: one wave per TWO rows; row1's raw loads issued before row0's
// compute so their HBM latency hides under it. NO launch_bounds: the R8
// cap (40 VGPR) spilled the whole pipeline to scratch (WRITE 346 MB).
// Natural allocation ~90 VGPR still gives 5-6 waves/SIMD.
// ---------------------------------------------------------------------------
template <bool USE_WS>
__global__
void qlayer_fused(const float* __restrict__ x, const float* __restrict__ Mtab,
                  const float* __restrict__ alphas, const float* __restrict__ betas,
                  const float* __restrict__ thetas, const float* __restrict__ phis,
                  float* __restrict__ out) {
    const int lane = threadIdx.x & 63;
    const int wv   = threadIdx.x >> 6;
    const int gw   = blockIdx.x * 4 + wv;   // global wave id, [0, 8192)
    const int row0 = gw * 2;

    const int o16 = orient_pls16((unsigned)lane);
    const int o32 = orient_pls32((unsigned)lane);

    const float* __restrict__ xr0 = x + (size_t)row0 * (2 * DIMQ);
    const float* __restrict__ xr1 = xr0 + 2 * DIMQ;
    float* __restrict__ or0       = out + (size_t)row0 * (2 * DIMQ);
    float* __restrict__ or1       = or0 + 2 * DIMQ;

    // Fallback matrices (identical in all lanes) when no workspace.
    float Ml[NQ * 8];
    if (!USE_WS) {
#pragma unroll
        for (int b = 0; b < NQ; ++b) {
            const int q = NQ - 1 - b;
            float sa, ca, sb, cb, st, ct, sp, cp;
            sincosf(alphas[q], &sa, &ca);
            sincosf(betas[q],  &sb, &cb);
            sincosf(thetas[q], &st, &ct);
            sincosf(phis[q],   &sp, &cp);
            const float2 u = make_float2(ca, sa), v = make_float2(cb, sb), p2 = make_float2(cp, sp);
            const float2 tm1  = make_float2(ct - 1.f, st);
            const float2 itp1 = make_float2(-st, ct + 1.f);
            const float2 omt  = make_float2(1.f - ct, -st);
            float2 m00 = cmulc(cmulc(p2, u), tm1);
            float2 m01 = cmulc(cmulc(p2, v), itp1);
            float2 m10 = cmulc(u, itp1);
            float2 m11 = cmulc(v, omt);
            Ml[b * 8 + 0] = m00.x * .5f; Ml[b * 8 + 1] = m00.y * .5f;
            Ml[b * 8 + 2] = m01.x * .5f; Ml[b * 8 + 3] = m01.y * .5f;
            Ml[b * 8 + 4] = m10.x * .5f; Ml[b * 8 + 5] = m10.y * .5f;
            Ml[b * 8 + 6] = m11.x * .5f; Ml[b * 8 + 7] = m11.y * .5f;
        }
    }

    // ---- software pipeline: load0 -> load1(issue) -> pack0 -> compute0 ->
    //      store0 -> pack1(waits) -> compute1 -> store1
    f32x4 raw0[2][4];
    load_raw(xr0, lane, raw0);
    f32x4 raw1[2][4];
    load_raw(xr1, lane, raw1);         // in flight during compute0

    f32x2 Pre[2][4], Pim[2][4];
    pack_raw(raw0, Pre, Pim);          // waits on row0's loads only

    apply_stages<USE_WS>(Pre, Pim, Mtab, Ml, lane, o16, o32);
    store_state(or0, lane, Pre, Pim);

    pack_raw(raw1, Pre, Pim);          // row1's loads long since landed
    apply_stages<USE_WS>(Pre, Pim, Mtab, Ml, lane, o16, o32);
    store_state(or1, lane, Pre, Pim);
}

extern "C" void kernel_launch(void* const* d_in, const int* in_sizes, int n_in,
                              void* d_out, int out_size, void* d_ws, size_t ws_size,
                              hipStream_t stream) {
    const float* x      = (const float*)d_in[0];
    const float* alphas = (const float*)d_in[1];
    const float* betas  = (const float*)d_in[2];
    const float* thetas = (const float*)d_in[3];
    const float* phis   = (const float*)d_in[4];
    float* out = (float*)d_out;

    const int blocks = BATCH_ROWS / 8;  // 4 waves/block, 2 rows/wave = 2048

    if (ws_size >= NQ * 8 * sizeof(float)) {
        float* M = (float*)d_ws;
        qmat_precompute<<<1, 64, 0, stream>>>(alphas, betas, thetas, phis, M);
        qlayer_fused<true><<<blocks, 256, 0, stream>>>(x, M, alphas, betas, thetas, phis, out);
    } else {
        qlayer_fused<false><<<blocks, 256, 0, stream>>>(x, nullptr, alphas, betas, thetas, phis, out);
    }
}